// Round 1
// baseline (80.105 us; speedup 1.0000x reference)
//
#include <hip/hip_runtime.h>
#include <hip/hip_bf16.h>
#include <cstdint>
#include <cstddef>

typedef float  f32x4  __attribute__((ext_vector_type(4)));
typedef __bf16 bf16x8 __attribute__((ext_vector_type(8)));
typedef __bf16 bf16x4 __attribute__((ext_vector_type(4)));

#define MFMA(a, b, c) __builtin_amdgcn_mfma_f32_16x16x32_bf16((a), (b), (c), 0, 0, 0)

#define B_     8
#define S_     2048
#define D_     1024
#define E_     64
#define YSZ    (B_ * S_ * D_)   // 16777216
#define WWARM  16
#define LCH    8

// ---------------- k_setup: convert weights to bf16 ----------------
__global__ __launch_bounds__(256) void k_setup(const float* __restrict__ w_in,
                                               const float* __restrict__ w_out,
                                               __bf16* __restrict__ winb,
                                               __bf16* __restrict__ wob) {
  const int i = blockIdx.x * 256 + threadIdx.x;   // grid 256 -> 65536 threads
  winb[i] = (__bf16)w_in[i];
  wob[i]  = (__bf16)w_out[i];
}

// ---------------- k_beta: beta = x @ w_in^T  (16384x1024x64) ----------------
// grid 256 blocks x 256 thr; block -> 64 rows x 64 cols; MFMA 16x16x32 bf16.
// All operands direct from global with 1-step register prefetch. No LDS.
__global__ __launch_bounds__(256) void k_beta(const float* __restrict__ x,
                                              const __bf16* __restrict__ winb,
                                              float* __restrict__ beta) {
  const int tid = threadIdx.x;
  const int w = tid >> 6, lane = tid & 63;
  const int u = lane >> 4, fl = lane & 15;
  const int rowA = blockIdx.x * 64 + w * 16 + fl;       // A rows: lane&15
  const float*  xp = x + (size_t)rowA * 1024 + u * 8;
  const __bf16* wp = winb + fl * 1024 + u * 8;          // + ct*16*1024 + k

  f32x4  acc[4] = {};
  f32x4  xc[2][2], xn[2][2];
  bf16x8 bc[4][2], bn[4][2];

#pragma unroll
  for (int kt = 0; kt < 2; kt++) {
    xc[kt][0] = *(const f32x4*)(xp + kt * 32);
    xc[kt][1] = *(const f32x4*)(xp + kt * 32 + 4);
  }
#pragma unroll
  for (int ct = 0; ct < 4; ct++)
#pragma unroll
    for (int kt = 0; kt < 2; kt++)
      bc[ct][kt] = *(const bf16x8*)(wp + ct * 16384 + kt * 32);

#pragma unroll
  for (int kk = 0; kk < 16; kk++) {
    if (kk < 15) {
      const int k1 = (kk + 1) * 64;
#pragma unroll
      for (int kt = 0; kt < 2; kt++) {
        xn[kt][0] = *(const f32x4*)(xp + k1 + kt * 32);
        xn[kt][1] = *(const f32x4*)(xp + k1 + kt * 32 + 4);
      }
#pragma unroll
      for (int ct = 0; ct < 4; ct++)
#pragma unroll
        for (int kt = 0; kt < 2; kt++)
          bn[ct][kt] = *(const bf16x8*)(wp + ct * 16384 + k1 + kt * 32);
    }
    bf16x8 af[2];
#pragma unroll
    for (int kt = 0; kt < 2; kt++)
#pragma unroll
      for (int j = 0; j < 4; j++) {
        af[kt][j]     = (__bf16)xc[kt][0][j];
        af[kt][j + 4] = (__bf16)xc[kt][1][j];
      }
#pragma unroll
    for (int ct = 0; ct < 4; ct++) {
      acc[ct] = MFMA(af[0], bc[ct][0], acc[ct]);
      acc[ct] = MFMA(af[1], bc[ct][1], acc[ct]);
    }
    if (kk < 15) {
#pragma unroll
      for (int kt = 0; kt < 2; kt++) { xc[kt][0] = xn[kt][0]; xc[kt][1] = xn[kt][1]; }
#pragma unroll
      for (int ct = 0; ct < 4; ct++) { bc[ct][0] = bn[ct][0]; bc[ct][1] = bn[ct][1]; }
    }
  }

  const int rowC = blockIdx.x * 64 + w * 16 + u * 4;    // C rows: (lane>>4)*4+reg
#pragma unroll
  for (int ct = 0; ct < 4; ct++)
#pragma unroll
    for (int r = 0; r < 4; r++)
      beta[(size_t)(rowC + r) * 64 + ct * 16 + fl] = acc[ct][r];
}

// ---------------- k_scan: truncated-memory parallel scan ----------------
// 128 blocks x 64 thr. Each block: 2 chunks (L=8) x 8 batches = N=16 columns,
// W=16 warm-up steps from zero (decay <= 0.4^16 ~ 4e-7, negligible).
// state^T (64 e x 16 bc), step:  rot = mc*r - ms*i + beta (f32, exact path),
// new = rot + rot @ E  via MFMA with A = (R - I)^T bf16, C-operand = rot f32.
__global__ __launch_bounds__(64) void k_scan(const float* __restrict__ beta,
                                             const float* __restrict__ resonance,
                                             const float* __restrict__ alpha,
                                             const float* __restrict__ omega,
                                             __bf16* __restrict__ states,
                                             float* __restrict__ outp) {
  const int lane = threadIdx.x;
  const int u = lane >> 4, fl = lane & 15;
  const int b = fl & 7, cslot = fl >> 3;
  const int c = blockIdx.x * 2 + cslot;

  // A[f][e] = R[e][f] - (e==f)
  bf16x8 afr[4][2];
#pragma unroll
  for (int mt = 0; mt < 4; mt++)
#pragma unroll
    for (int kt = 0; kt < 2; kt++)
#pragma unroll
      for (int j = 0; j < 8; j++) {
        const int e = kt * 32 + u * 8 + j;
        const int f = mt * 16 + fl;
        float v = resonance[e * 64 + f];
        if (e == f) v -= 1.0f;
        afr[mt][kt][j] = (__bf16)v;
      }

  float mcv[4][4], msv[4][4];   // mag*cos, mag*sin at f = mt*16 + u*4 + r
#pragma unroll
  for (int mt = 0; mt < 4; mt++)
#pragma unroll
    for (int r = 0; r < 4; r++) {
      const int fr = mt * 16 + u * 4 + r;
      const float mg = 1.0f / (1.0f + expf(-alpha[fr]));
      mcv[mt][r] = mg * cosf(omega[fr]);
      msv[mt][r] = mg * sinf(omega[fr]);
    }

  __shared__ __bf16 lsr[16][72];   // [bc][e], pad 72 -> <=2-way bank aliasing
  __shared__ __bf16 lsi[16][72];

  f32x4 sr[4] = {};
  f32x4 si[4] = {};
  const int brow = b * S_;

  for (int s = 0; s < WWARM + LCH; s++) {
    const int t = c * LCH - WWARM + s;
    f32x4 bt[4] = {};
    if (t >= 0) {
#pragma unroll
      for (int mt = 0; mt < 4; mt++)
        bt[mt] = *(const f32x4*)(beta + (size_t)(brow + t) * 64 + mt * 16 + u * 4);
    }
    f32x4 rr[4], ri[4];
#pragma unroll
    for (int mt = 0; mt < 4; mt++)
#pragma unroll
      for (int r = 0; r < 4; r++) {
        rr[mt][r] = mcv[mt][r] * sr[mt][r] - msv[mt][r] * si[mt][r] + bt[mt][r];
        ri[mt][r] = msv[mt][r] * sr[mt][r] + mcv[mt][r] * si[mt][r];
      }
    // stage rotated state (bf16) for the B-operand transpose
#pragma unroll
    for (int mt = 0; mt < 4; mt++) {
      bf16x4 pr, pi;
#pragma unroll
      for (int r = 0; r < 4; r++) { pr[r] = (__bf16)rr[mt][r]; pi[r] = (__bf16)ri[mt][r]; }
      *(bf16x4*)&lsr[fl][mt * 16 + u * 4] = pr;
      *(bf16x4*)&lsi[fl][mt * 16 + u * 4] = pi;
    }
    __syncthreads();
    bf16x8 brf[2], bif[2];
#pragma unroll
    for (int kt = 0; kt < 2; kt++) {
      brf[kt] = *(const bf16x8*)&lsr[fl][kt * 32 + u * 8];
      bif[kt] = *(const bf16x8*)&lsi[fl][kt * 32 + u * 8];
    }
#pragma unroll
    for (int mt = 0; mt < 4; mt++) {
      f32x4 dr = MFMA(afr[mt][0], brf[0], rr[mt]);
      sr[mt]   = MFMA(afr[mt][1], brf[1], dr);
      f32x4 di = MFMA(afr[mt][0], bif[0], ri[mt]);
      si[mt]   = MFMA(afr[mt][1], bif[1], di);
    }
    if (s >= WWARM) {
#pragma unroll
      for (int mt = 0; mt < 4; mt++) {
        bf16x4 p;
#pragma unroll
        for (int r = 0; r < 4; r++) p[r] = (__bf16)sr[mt][r];
        *(bf16x4*)(states + (size_t)(brow + t) * 64 + mt * 16 + u * 4) = p;
      }
    }
    __syncthreads();
  }

  if (c == S_ / LCH - 1) {   // final chunk: write r_fin, i_fin (f32)
#pragma unroll
    for (int mt = 0; mt < 4; mt++)
#pragma unroll
      for (int r = 0; r < 4; r++) {
        const int f = mt * 16 + u * 4 + r;
        outp[YSZ + b * 64 + f]       = sr[mt][r];
        outp[YSZ + 512 + b * 64 + f] = si[mt][r];
      }
  }
}

// ---------------- k_y: y = states @ w_out^T fused with LayerNorm ----------------
// grid 512 x 256 thr; block -> 32 rows x full 1024 cols (wave w: cols 256w..256w+255)
__global__ __launch_bounds__(256) void k_y(const __bf16* __restrict__ states,
                                           const __bf16* __restrict__ wob,
                                           const float* __restrict__ gamma,
                                           const float* __restrict__ lbeta,
                                           float* __restrict__ y) {
  const int tid = threadIdx.x;
  const int w = tid >> 6, lane = tid & 63;
  const int u = lane >> 4, fl = lane & 15;
  const int rowbase = blockIdx.x * 32;

  bf16x8 ar[2][2];
#pragma unroll
  for (int rt = 0; rt < 2; rt++)
#pragma unroll
    for (int kt = 0; kt < 2; kt++)
      ar[rt][kt] = *(const bf16x8*)(states + (size_t)(rowbase + rt * 16 + fl) * 64 + kt * 32 + u * 8);

  const __bf16* wp = wob + (size_t)(w * 256 + fl) * 64 + u * 8;  // + ct*1024 + kt*32

  f32x4 acc[2][16] = {};
  bf16x8 bcur[2], bnext[2];
#pragma unroll
  for (int kt = 0; kt < 2; kt++) bcur[kt] = *(const bf16x8*)(wp + kt * 32);

#pragma unroll
  for (int ct = 0; ct < 16; ct++) {
    if (ct < 15) {
#pragma unroll
      for (int kt = 0; kt < 2; kt++) bnext[kt] = *(const bf16x8*)(wp + (ct + 1) * 1024 + kt * 32);
    }
#pragma unroll
    for (int rt = 0; rt < 2; rt++) {
      acc[rt][ct] = MFMA(ar[rt][0], bcur[0], acc[rt][ct]);
      acc[rt][ct] = MFMA(ar[rt][1], bcur[1], acc[rt][ct]);
    }
    if (ct < 15) { bcur[0] = bnext[0]; bcur[1] = bnext[1]; }
  }

  // LayerNorm over d: per-row sums
  float s1[2][4], s2[2][4];
#pragma unroll
  for (int rt = 0; rt < 2; rt++)
#pragma unroll
    for (int r = 0; r < 4; r++) {
      float a = 0.f, q = 0.f;
#pragma unroll
      for (int ct = 0; ct < 16; ct++) {
        const float v = acc[rt][ct][r];
        a += v; q += v * v;
      }
      s1[rt][r] = a; s2[rt][r] = q;
    }
#pragma unroll
  for (int m = 1; m < 16; m <<= 1) {
#pragma unroll
    for (int rt = 0; rt < 2; rt++)
#pragma unroll
      for (int r = 0; r < 4; r++) {
        s1[rt][r] += __shfl_xor(s1[rt][r], m, 64);
        s2[rt][r] += __shfl_xor(s2[rt][r], m, 64);
      }
  }
  __shared__ float pS1[4][32];
  __shared__ float pS2[4][32];
  if (fl == 0) {
#pragma unroll
    for (int rt = 0; rt < 2; rt++)
#pragma unroll
      for (int r = 0; r < 4; r++) {
        pS1[w][rt * 16 + u * 4 + r] = s1[rt][r];
        pS2[w][rt * 16 + u * 4 + r] = s2[rt][r];
      }
  }
  __syncthreads();
  float mu[2][4], rs[2][4];
#pragma unroll
  for (int rt = 0; rt < 2; rt++)
#pragma unroll
    for (int r = 0; r < 4; r++) {
      const int rl = rt * 16 + u * 4 + r;
      float S1 = 0.f, S2 = 0.f;
#pragma unroll
      for (int ww = 0; ww < 4; ww++) { S1 += pS1[ww][rl]; S2 += pS2[ww][rl]; }
      const float m  = S1 * (1.0f / 1024.0f);
      const float va = S2 * (1.0f / 1024.0f) - m * m;
      mu[rt][r] = m;
      rs[rt][r] = rsqrtf(va + 1e-5f);
    }
#pragma unroll
  for (int ct = 0; ct < 16; ct++) {
    const int d = w * 256 + ct * 16 + fl;
    const float gv = gamma[d], bv = lbeta[d];
#pragma unroll
    for (int rt = 0; rt < 2; rt++)
#pragma unroll
      for (int r = 0; r < 4; r++) {
        const float v = (acc[rt][ct][r] - mu[rt][r]) * rs[rt][r] * gv + bv;
        y[(size_t)(rowbase + rt * 16 + u * 4 + r) * 1024 + d] = v;
      }
  }
}

extern "C" void kernel_launch(void* const* d_in, const int* in_sizes, int n_in,
                              void* d_out, int out_size, void* d_ws, size_t ws_size,
                              hipStream_t stream) {
  const float* x         = (const float*)d_in[0];
  const float* alpha     = (const float*)d_in[1];
  const float* omega     = (const float*)d_in[2];
  const float* w_in      = (const float*)d_in[3];
  const float* w_out     = (const float*)d_in[4];
  const float* resonance = (const float*)d_in[5];
  const float* ln_g      = (const float*)d_in[6];
  const float* ln_b      = (const float*)d_in[7];
  float* out = (float*)d_out;

  char* ws = (char*)d_ws;
  float*  beta   = (float*)ws;                                   // 4 MB
  __bf16* states = (__bf16*)(ws + (4u << 20));                   // 2 MB
  __bf16* winb   = (__bf16*)(ws + (6u << 20));                   // 128 KB
  __bf16* wob    = (__bf16*)(ws + (6u << 20) + (128u << 10));    // 128 KB

  k_setup<<<256, 256, 0, stream>>>(w_in, w_out, winb, wob);
  k_beta<<<256, 256, 0, stream>>>(x, winb, beta);
  k_scan<<<128, 64, 0, stream>>>(beta, resonance, alpha, omega, states, out);
  k_y<<<512, 256, 0, stream>>>(states, wob, ln_g, ln_b, out);
}